// Round 10
// baseline (339.118 us; speedup 1.0000x reference)
//
#include <hip/hip_runtime.h>
#include <hip/hip_fp16.h>
#include <cmath>

#define EPS 1e-5f
#define TAU 0.15f
#define RP  8

// Problem constants (fixed instance)
#define Bn 16
#define Dn 256
#define Tn 4096
#define Kn 2048

typedef unsigned short ushort_t;
typedef __attribute__((ext_vector_type(8))) _Float16 f16x8;
typedef __attribute__((ext_vector_type(4))) float f32x4;

__device__ __forceinline__ unsigned short f2h(float v) {
    return __half_as_ushort(__float2half_rn(v));
}

// fp16 rounded UP in value (result >= v).  Verified in the R1 record path.
__device__ __forceinline__ unsigned short f16_up(float v) {
    const __half h = __float2half_rn(v);
    const float back = __half2float(h);
    unsigned short u = __half_as_ushort(h);
    if (back < v) u = (u & 0x8000u) ? (u - 1) : (u + 1);
    return u;
}

#define GLOAD_LDS16(gp, lp) __builtin_amdgcn_global_load_lds( \
    (const __attribute__((address_space(1))) unsigned int*)(gp), \
    (__attribute__((address_space(3))) unsigned int*)(lp), 16, 0, 0)

// ---------------------------------------------------------------------------
// Kernel 1: prep — emb = es/max(usage,eps); e16 fp16 plane; bias = 0.5|e|^2;
// embT4 transpose. (unchanged)
// ---------------------------------------------------------------------------
__global__ __launch_bounds__(256) void prep_kernel(
    const float* __restrict__ es, const float* __restrict__ usage,
    float* __restrict__ emb, ushort_t* __restrict__ e16,
    float* __restrict__ bias, float4* __restrict__ embT4,
    int* __restrict__ counter)
{
    __shared__ float sh[256];
    __shared__ float wsum[4];
    const int k = blockIdx.x;
    const int d = threadIdx.x;
    const float inv = 1.0f / fmaxf(usage[k], EPS);
    const float v = es[(size_t)k * Dn + d] * inv;
    emb[(size_t)k * Dn + d] = v;
    e16[(size_t)k * Dn + d] = f2h(fminf(fmaxf(v, -65504.f), 65504.f));
    sh[d] = v;
    float sq = v * v;
    #pragma unroll
    for (int off = 32; off > 0; off >>= 1) sq += __shfl_down(sq, off, 64);
    const int lane = d & 63, wv = d >> 6;
    if (lane == 0) wsum[wv] = sq;
    __syncthreads();
    if (d < 64)
        embT4[(size_t)d * Kn + k] = make_float4(sh[4*d], sh[4*d+1], sh[4*d+2], sh[4*d+3]);
    if (d == 0) {
        bias[k] = 0.5f * (wsum[0] + wsum[1] + wsum[2] + wsum[3]);
        if (k == 0) *counter = 0;
    }
}

// ---------------------------------------------------------------------------
// Kernel 3 (R5 BODY + K-SPLIT x2 FOR CO-RESIDENCY): per-wave structure is
// byte-identical to the verified 140 µs round-5 kernel (8 waves x 32t,
// af 64 VGPR in regs from x, acc 64, 2x32 KB XOR-swizzled double-buffered
// B, counted vmcnt).  Grid = 512: block = one 256-t tile x ONE K-HALF
// (8 kc chunks of 128 k).  TWO blocks co-resident per CU (LDS 73728 x 2 =
// 147456 <= 163840; 16 waves/CU x 192 unified regs fits) — independent
// barrier domains overlap each other's vmcnt/barrier/drain bubbles, which
// R9 counters show are ~40% of phase time.  kh = bid>>8 keeps a tile's two
// k-siblings on the same XCD (shared A-tile reads hit L2/L3).
// Output: 2 slot-major uint2 records per point (exact fp32 s1; f16-up s2;
// k in low 16 bits) — R1's verified record format; merged by merge_kernel.
//
// vmcnt ledger (per thread) — unchanged from R5, loop is 8 kc not 16:
//   prologue: bias gload_lds (1) + 128 A scalar loads; vmcnt(0); barrier;
//     stage B(g0,h0)(4), B(g0,h1)(4) -> 8 outstanding.
//   kc-phase h0: vmcnt(4) [Bs0 ready], barrier, compute, barrier,
//                restage Bs0 <- B(g+1,h0) (4)  [kc<7]
//   kc-phase h1: vmcnt(4) (kc<7) / vmcnt(0) (kc=7), barrier, compute,
//                barrier, restage Bs1 <- B(g+1,h1) (4) [kc<7]
// ---------------------------------------------------------------------------
#define BARRIER_PIN()                                                         \
    __builtin_amdgcn_s_barrier();                                             \
    __builtin_amdgcn_sched_barrier(0)

// stage 32 KB B-chunk (global 128-k chunk gc, 128 d half) w/ inverse swizzle
#define STAGE_B(dst, gc, hh)                                                  \
    {                                                                         \
        _Pragma("unroll")                                                     \
        for (int r = 0; r < 4; ++r) {                                         \
            const int c   = r * 512 + tid;                                    \
            const int row = c >> 4;                                           \
            const int col = (((c & 15) ^ (row & 15)) << 3);                   \
            GLOAD_LDS16(e16 + ((size_t)((gc) * 128 + row)) * Dn + (hh) * 128 + col, \
                        (dst) + ((r * 512 + (wid << 6)) << 3));               \
        }                                                                     \
    }

// plain accumulate phase (d-half via afArr, B from bbuf)
#define COMPUTE_ACC(bbuf, afArr)                                              \
    {                                                                         \
        __builtin_amdgcn_s_setprio(1);                                        \
        _Pragma("unroll")                                                     \
        for (int ks = 0; ks < 4; ++ks)                                        \
            _Pragma("unroll")                                                 \
            for (int j = 0; j < 8; ++j) {                                     \
                const f16x8 bf = *(const f16x8*)(                             \
                    &(bbuf)[((j << 4) + l15) * 128 +                          \
                            ((((ks << 2) | quad) ^ l15) << 3)]);              \
                _Pragma("unroll")                                             \
                for (int i = 0; i < 2; ++i)                                   \
                    acc[i][j] = __builtin_amdgcn_mfma_f32_16x16x32_f16(       \
                        afArr[ks * 2 + i], bf, acc[i][j], 0, 0, 0);           \
            }                                                                 \
        __builtin_amdgcn_s_setprio(0);                                        \
    }

__global__ __launch_bounds__(512, 2) void gemm_argmax(
    const float* __restrict__ x, const ushort_t* __restrict__ e16,
    const float* __restrict__ bias_g, uint2* __restrict__ rec)
{
    __shared__ __align__(16) ushort_t BsS[2][128 * 128]; // 2 x 32 KB
    __shared__ __align__(16) float    biasLds[2048];     // 8 KB

    const int bid  = blockIdx.x;         // 512 blocks
    const int kh   = bid >> 8;           // k-half; siblings share XCD
    const int tile = bid & 255;
    const int b    = tile >> 4;
    const int tt   = tile & 15;
    const int t0   = tt << 8;
    const int kc0  = kh << 3;            // global 128-k chunk base

    const int tid  = threadIdx.x;
    const int lane = tid & 63;
    const int wid  = tid >> 6;           // 8 waves, each owns 32 t-rows
    const int l15  = lane & 15;
    const int quad = lane >> 4;
    const int wm   = wid;                // t-block of 32 rows

    const size_t bTt0 = (size_t)b * Tn + t0;

    // ---- prologue: bias -> LDS; A -> registers directly from x ----
    GLOAD_LDS16(bias_g + (tid << 2), biasLds + (wid << 8));   // 1 outstanding

    // persistent A fragments: 2 halves x (4 ks x 2 i) = 16 f16x8 = 64 VGPR
    f16x8 af0[8], af1[8];
    {
        const float* xb = x + (size_t)b * Dn * Tn;   // [D][T]
        #pragma unroll
        for (int ks = 0; ks < 4; ++ks)
            #pragma unroll
            for (int i = 0; i < 2; ++i) {
                const int t = t0 + (wm << 5) + (i << 4) + l15;
                const float* c0 = xb + ((size_t)(ks * 32 + quad * 8)) * Tn + t;
                const float* c1 = c0 + (size_t)128 * Tn;
                f16x8 v0, v1;
                #pragma unroll
                for (int e = 0; e < 8; ++e) {
                    v0[e] = (_Float16)c0[(size_t)e * Tn];
                    v1[e] = (_Float16)c1[(size_t)e * Tn];
                }
                af0[ks * 2 + i] = v0;
                af1[ks * 2 + i] = v1;
            }
    }

    // accumulators: 2 i x 8 j = 64 regs
    f32x4 acc[2][8];
    // top-2 state per (i,r): 24 regs
    float S1[2][4], S2[2][4];
    int   K1[2][4];
    #pragma unroll
    for (int i = 0; i < 2; ++i)
        #pragma unroll
        for (int r = 0; r < 4; ++r) { S1[i][r] = -INFINITY; S2[i][r] = -INFINITY; K1[i][r] = 0; }
    #pragma unroll
    for (int i = 0; i < 2; ++i)
        #pragma unroll
        for (int j = 0; j < 8; ++j)
            acc[i][j] = (f32x4){-INFINITY, -INFINITY, -INFINITY, -INFINITY};

    asm volatile("s_waitcnt vmcnt(0)" ::: "memory");   // bias + A loads landed
    BARRIER_PIN();                                     // biasLds visible
    STAGE_B(&BsS[0][0], kc0, 0);                       // 4
    STAGE_B(&BsS[1][0], kc0, 1);                       // 4 -> 8 outstanding

    #pragma unroll 1
    for (int kc = 0; kc < 8; ++kc) {
        const int g = kc0 + kc;          // global 128-k chunk

        // ---- phase h0 (d 0..127, Bs0): drain prev-kc acc + C=-bias re-init --
        asm volatile("s_waitcnt vmcnt(4)" ::: "memory");
        BARRIER_PIN();
        {
            float bj[8];
            #pragma unroll
            for (int j = 0; j < 8; ++j)
                bj[j] = biasLds[(g << 7) + (j << 4) + l15];
            const int kdrb = ((g - 1) << 7) + l15;   // k of drained values
            __builtin_amdgcn_s_setprio(1);
            #pragma unroll
            for (int j = 0; j < 8; ++j) {
                const f16x8 bf0 = *(const f16x8*)(
                    &BsS[0][((j << 4) + l15) * 128 + ((quad ^ l15) << 3)]);
                const float nb = -bj[j];
                const f32x4 cin = {nb, nb, nb, nb};
                const int kdr = kdrb + (j << 4);
                #pragma unroll
                for (int i = 0; i < 2; ++i) {
                    // drain old acc[i][j]: med3 top-2 insert (kc==0: -INF, harmless)
                    #pragma unroll
                    for (int r = 0; r < 4; ++r) {
                        const float s = acc[i][j][r];
                        S2[i][r] = __builtin_amdgcn_fmed3f(s, S1[i][r], S2[i][r]);
                        const bool gt = s > S1[i][r];
                        K1[i][r] = gt ? kdr : K1[i][r];
                        S1[i][r] = fmaxf(S1[i][r], s);
                    }
                    acc[i][j] = __builtin_amdgcn_mfma_f32_16x16x32_f16(
                        af0[i], bf0, cin, 0, 0, 0);
                }
            }
            #pragma unroll
            for (int ks = 1; ks < 4; ++ks)
                #pragma unroll
                for (int j = 0; j < 8; ++j) {
                    const f16x8 bf = *(const f16x8*)(
                        &BsS[0][((j << 4) + l15) * 128 +
                                ((((ks << 2) | quad) ^ l15) << 3)]);
                    #pragma unroll
                    for (int i = 0; i < 2; ++i)
                        acc[i][j] = __builtin_amdgcn_mfma_f32_16x16x32_f16(
                            af0[ks * 2 + i], bf, acc[i][j], 0, 0, 0);
                }
            __builtin_amdgcn_s_setprio(0);
        }
        BARRIER_PIN();                       // WAR: Bs0 readers done
        if (kc < 7) STAGE_B(&BsS[0][0], g + 1, 0);

        // ---- phase h1 (d 128..255, Bs1): plain accumulate ----
        if (kc < 7) { asm volatile("s_waitcnt vmcnt(4)" ::: "memory"); }
        else        { asm volatile("s_waitcnt vmcnt(0)" ::: "memory"); }
        BARRIER_PIN();
        COMPUTE_ACC((&BsS[1][0]), af1);
        BARRIER_PIN();                       // WAR: Bs1 readers done
        if (kc < 7) STAGE_B(&BsS[1][0], g + 1, 1);
    }

    __builtin_amdgcn_sched_barrier(0);

    // ---- final drain of last chunk's acc ----
    {
        const int kfb = ((kc0 + 7) << 7) + l15;
        #pragma unroll
        for (int j = 0; j < 8; ++j) {
            const int kf = kfb + (j << 4);
            #pragma unroll
            for (int i = 0; i < 2; ++i)
                #pragma unroll
                for (int r = 0; r < 4; ++r) {
                    const float s = acc[i][j][r];
                    S2[i][r] = __builtin_amdgcn_fmed3f(s, S1[i][r], S2[i][r]);
                    const bool gt = s > S1[i][r];
                    K1[i][r] = gt ? kf : K1[i][r];
                    S1[i][r] = fmaxf(S1[i][r], s);
                }
        }
    }

    // ---- butterfly across the 16 k-lanes (tie-break: lowest k) ----
    #pragma unroll
    for (int m = 1; m <= 8; m <<= 1) {
        #pragma unroll
        for (int i = 0; i < 2; ++i)
            #pragma unroll
            for (int r = 0; r < 4; ++r) {
                const float os1 = __shfl_xor(S1[i][r], m);
                const float os2 = __shfl_xor(S2[i][r], m);
                const int   ok1 = __shfl_xor(K1[i][r], m);
                const bool take = (os1 > S1[i][r]) || (os1 == S1[i][r] && ok1 < K1[i][r]);
                const float ns2 = take ? fmaxf(S1[i][r], os2) : fmaxf(S2[i][r], os1);
                if (take) { S1[i][r] = os1; K1[i][r] = ok1; }
                S2[i][r] = ns2;
            }
    }

    if (l15 == 0) {
        #pragma unroll
        for (int i = 0; i < 2; ++i)
            #pragma unroll
            for (int r = 0; r < 4; ++r) {
                const int row = (wm << 5) + (i << 4) + (quad << 2) + r;
                const size_t p = bTt0 + row;
                uint2 e;
                e.x = __float_as_uint(S1[i][r]);
                e.y = ((unsigned)f16_up(S2[i][r]) << 16) | (unsigned)K1[i][r];
                rec[(size_t)kh * (Bn * Tn) + p] = e;
            }
    }
}

// ---------------------------------------------------------------------------
// Kernel 4: merge the 2 slot-major records per point (R1-verified logic,
// NSLOT=2).  Non-winner slot contributes exact fp32 s1; winner's s2 is an
// f16 upper bound (conservative -> only extra rescues).
// ---------------------------------------------------------------------------
__global__ __launch_bounds__(256) void merge_kernel(
    const uint2* __restrict__ rec, int* __restrict__ codes_i,
    float* __restrict__ codes_f, int* __restrict__ list, int* __restrict__ counter)
{
    const int p = blockIdx.x * 256 + threadIdx.x;
    uint2 e = rec[p];
    float g1 = __uint_as_float(e.x);
    float g2 = __half2float(__ushort_as_half((unsigned short)(e.y >> 16)));
    int kk = (int)(e.y & 0xffffu);
    e = rec[(size_t)(Bn * Tn) + p];                  // slot 1 (higher k)
    const float s1 = __uint_as_float(e.x);
    if (s1 > g1) {
        const float s2u = __half2float(__ushort_as_half((unsigned short)(e.y >> 16)));
        g2 = fmaxf(fmaxf(g2, g1), s2u);
        g1 = s1;
        kk = (int)(e.y & 0xffffu);
    } else {
        g2 = fmaxf(g2, s1);
    }
    codes_i[p] = kk;
    codes_f[p] = (float)kk;
    if (g1 - g2 < TAU) {
        const int idx = atomicAdd(counter, 1);
        list[idx] = p;
    }
}

// ---------------------------------------------------------------------------
// Kernel 5: exact fp32 rescore (unchanged)
// ---------------------------------------------------------------------------
__global__ __launch_bounds__(256) void rescue_kernel(
    const float* __restrict__ x, const float4* __restrict__ embT4,
    const float* __restrict__ bias, const int* __restrict__ list,
    const int* __restrict__ counter, int* __restrict__ codes_i,
    float* __restrict__ codes_f)
{
    __shared__ float xv[RP][256];
    __shared__ int plist[RP];
    __shared__ float rs[RP][4];
    __shared__ int   rk[RP][4];
    const int tid = threadIdx.x, lane = tid & 63, wid = tid >> 6;
    const int count = *counter;
    for (int base = blockIdx.x * RP; base < count; base += gridDim.x * RP) {
        const int npts = min(RP, count - base);
        __syncthreads();
        if (tid < npts) plist[tid] = list[base + tid];
        __syncthreads();
        for (int pi = 0; pi < npts; ++pi) {
            const int p = plist[pi];
            xv[pi][tid] = x[((size_t)((p >> 12) * Dn + tid)) * Tn + (p & 4095)];
        }
        for (int pi = npts; pi < RP; ++pi) xv[pi][tid] = 0.f;
        __syncthreads();

        float acc[8][RP];
        #pragma unroll
        for (int s = 0; s < 8; ++s)
            #pragma unroll
            for (int pi = 0; pi < RP; ++pi) acc[s][pi] = 0.f;

        for (int dc = 0; dc < 64; ++dc) {
            float4 ev[8];
            #pragma unroll
            for (int s = 0; s < 8; ++s)
                ev[s] = embT4[(size_t)dc * Kn + tid + (s << 8)];
            #pragma unroll
            for (int pi = 0; pi < RP; ++pi) {
                const float4 xw = *(const float4*)&xv[pi][dc << 2];
                #pragma unroll
                for (int s = 0; s < 8; ++s)
                    acc[s][pi] += ev[s].x * xw.x + ev[s].y * xw.y
                                + ev[s].z * xw.z + ev[s].w * xw.w;
            }
        }

        float bs[RP]; int bk[RP];
        #pragma unroll
        for (int pi = 0; pi < RP; ++pi) { bs[pi] = -INFINITY; bk[pi] = 0; }
        #pragma unroll
        for (int s = 0; s < 8; ++s) {
            const int kk = tid + (s << 8);
            const float bv = bias[kk];
            #pragma unroll
            for (int pi = 0; pi < RP; ++pi) {
                const float sc = acc[s][pi] - bv;
                if (sc > bs[pi]) { bs[pi] = sc; bk[pi] = kk; }
            }
        }
        #pragma unroll
        for (int off = 1; off < 64; off <<= 1) {
            #pragma unroll
            for (int pi = 0; pi < RP; ++pi) {
                const float os = __shfl_xor(bs[pi], off);
                const int   ok = __shfl_xor(bk[pi], off);
                if (os > bs[pi] || (os == bs[pi] && ok < bk[pi])) { bs[pi] = os; bk[pi] = ok; }
            }
        }
        if (lane == 0) {
            #pragma unroll
            for (int pi = 0; pi < RP; ++pi) { rs[pi][wid] = bs[pi]; rk[pi][wid] = bk[pi]; }
        }
        __syncthreads();
        if (tid < npts) {
            float fs = rs[tid][0]; int fk = rk[tid][0];
            #pragma unroll
            for (int w = 1; w < 4; ++w) {
                if (rs[tid][w] > fs || (rs[tid][w] == fs && rk[tid][w] < fk)) {
                    fs = rs[tid][w]; fk = rk[tid][w];
                }
            }
            const int p = plist[tid];
            codes_i[p] = fk;
            codes_f[p] = (float)fk;
        }
    }
}

// ---------------------------------------------------------------------------
// Kernel 6: decode — d-range split across gridDim.z (4 blocks/CU for TLP)
// ---------------------------------------------------------------------------
__global__ __launch_bounds__(256) void decode_kernel(
    const float* __restrict__ emb, const int* __restrict__ codes,
    float* __restrict__ out)
{
    const int b = blockIdx.y;
    const int t = blockIdx.x * 256 + threadIdx.x;
    const int z16 = blockIdx.z * 16;             // float4-index base (16 per z)
    const int c = codes[(size_t)b * Tn + t];
    const float4* e4 = (const float4*)(emb + (size_t)c * Dn);
    float* ob = out + (size_t)b * Dn * Tn + t;
    #pragma unroll 4
    for (int q = 0; q < 16; ++q) {
        const int d4 = z16 + q;
        const float4 v = e4[d4];
        ob[(size_t)(d4 * 4 + 0) * Tn] = v.x;
        ob[(size_t)(d4 * 4 + 1) * Tn] = v.y;
        ob[(size_t)(d4 * 4 + 2) * Tn] = v.z;
        ob[(size_t)(d4 * 4 + 3) * Tn] = v.w;
    }
}

// ---------------------------------------------------------------------------
extern "C" void kernel_launch(void* const* d_in, const int* in_sizes, int n_in,
                              void* d_out, int out_size, void* d_ws, size_t ws_size,
                              hipStream_t stream) {
    const float* x     = (const float*)d_in[0];   // [B, D, T]
    const float* es    = (const float*)d_in[1];   // [K, D]
    const float* usage = (const float*)d_in[2];   // [K]

    // ws layout (byte offsets, 16-aligned) — ~6 MiB
    char* ws = (char*)d_ws;
    float*    emb     = (float*)(ws + 0);                // 2 MiB
    float*    bias    = (float*)(ws + 2097152);          // 8 KB
    ushort_t* e16     = (ushort_t*)(ws + 2105344);       // 1 MiB
    float4*   embT4   = (float4*)(ws + 3153920);         // 2 MiB
    int*      codes_i = (int*)(ws + 5251072);            // 256 KB
    int*      list    = (int*)(ws + 5513216);            // 256 KB
    int*      counter = (int*)(ws + 5775360);            // 4 B

    float* codes_f = (float*)d_out;                      // [B*T]
    float* decoded = (float*)d_out + (size_t)Bn * Tn;    // [B*D*T], 64 MiB

    // rec (2 slots x 512 KB = 1 MiB) lives inside the decoded region;
    // consumed by merge_kernel before decode overwrites it.
    uint2* rec = (uint2*)decoded;

    prep_kernel<<<Kn, 256, 0, stream>>>(es, usage, emb, e16, bias, embT4, counter);

    // 512 blocks of 512 thr (TWO per CU), each: 256 t x one K-half (1024),
    // 8 waves x 32 t-rows, A in registers — R5 body, k-split grid
    gemm_argmax<<<512, 512, 0, stream>>>(x, e16, bias, rec);

    merge_kernel<<<(Bn * Tn) / 256, 256, 0, stream>>>(rec, codes_i, codes_f,
                                                      list, counter);

    rescue_kernel<<<1024, 256, 0, stream>>>(x, embT4, bias, list, counter, codes_i, codes_f);

    dim3 g6(Tn / 256, Bn, 4);
    decode_kernel<<<g6, 256, 0, stream>>>(emb, codes_i, decoded);
}

// Round 11
// 296.668 us; speedup vs baseline: 1.1431x; 1.1431x over previous
//
#include <hip/hip_runtime.h>
#include <hip/hip_fp16.h>
#include <cmath>

#define EPS 1e-5f
#define TAU 0.15f
#define RP  8

// Problem constants (fixed instance)
#define Bn 16
#define Dn 256
#define Tn 4096
#define Kn 2048

typedef unsigned short ushort_t;
typedef __attribute__((ext_vector_type(8))) _Float16 f16x8;
typedef __attribute__((ext_vector_type(4))) float f32x4;

__device__ __forceinline__ unsigned short f2h(float v) {
    return __half_as_ushort(__float2half_rn(v));
}

#define GLOAD_LDS16(gp, lp) __builtin_amdgcn_global_load_lds( \
    (const __attribute__((address_space(1))) unsigned int*)(gp), \
    (__attribute__((address_space(3))) unsigned int*)(lp), 16, 0, 0)

// ---------------------------------------------------------------------------
// Kernel 1: prep — emb = es/max(usage,eps); e16 fp16 plane; bias = 0.5|e|^2;
// embT4 transpose. (unchanged)
// ---------------------------------------------------------------------------
__global__ __launch_bounds__(256) void prep_kernel(
    const float* __restrict__ es, const float* __restrict__ usage,
    float* __restrict__ emb, ushort_t* __restrict__ e16,
    float* __restrict__ bias, float4* __restrict__ embT4,
    int* __restrict__ counter)
{
    __shared__ float sh[256];
    __shared__ float wsum[4];
    const int k = blockIdx.x;
    const int d = threadIdx.x;
    const float inv = 1.0f / fmaxf(usage[k], EPS);
    const float v = es[(size_t)k * Dn + d] * inv;
    emb[(size_t)k * Dn + d] = v;
    e16[(size_t)k * Dn + d] = f2h(fminf(fmaxf(v, -65504.f), 65504.f));
    sh[d] = v;
    float sq = v * v;
    #pragma unroll
    for (int off = 32; off > 0; off >>= 1) sq += __shfl_down(sq, off, 64);
    const int lane = d & 63, wv = d >> 6;
    if (lane == 0) wsum[wv] = sq;
    __syncthreads();
    if (d < 64)
        embT4[(size_t)d * Kn + k] = make_float4(sh[4*d], sh[4*d+1], sh[4*d+2], sh[4*d+3]);
    if (d == 0) {
        bias[k] = 0.5f * (wsum[0] + wsum[1] + wsum[2] + wsum[3]);
        if (k == 0) *counter = 0;
    }
}

// ---------------------------------------------------------------------------
// Kernel 3 (R9 BODY + FUSED DECODE EPILOGUE): the verified 142 µs full-K
// kernel (256t tile, 8 waves x 32t, A in regs from x, 2x32 KB XOR-swizzled
// double-buffered B, counted vmcnt, grid 256 = 1/CU) — occupancy quantum
// (m69 bins: 129-256 regs -> 8 waves/CU) makes this the fixed point; all
// co-residency/repack variants measured worse (R4/R6/R7/R8/R10).
// NEW: after the butterfly, codes go to LDS and the block writes its own
// 256 decoded columns (512 thr x 128 floats, t-coalesced) — the decode
// kernel, its launch gap, and its codes/emb re-reads are deleted.  rescue
// rewrites decoded columns for the (few) rescued points afterward.
//
// vmcnt ledger (per thread) — unchanged:
//   prologue: bias gload_lds (1) + 128 A scalar loads; vmcnt(0); barrier;
//     stage B(0,h0)(4), B(0,h1)(4) -> 8 outstanding.
//   kc-phase h0: vmcnt(4) [Bs0 ready], barrier, compute, barrier,
//                restage Bs0 <- B(kc+1,h0) (4)  [kc<15]
//   kc-phase h1: vmcnt(4) (kc<15) / vmcnt(0) (kc=15), barrier, compute,
//                barrier, restage Bs1 <- B(kc+1,h1) (4) [kc<15]
// ---------------------------------------------------------------------------
#define BARRIER_PIN()                                                         \
    __builtin_amdgcn_s_barrier();                                             \
    __builtin_amdgcn_sched_barrier(0)

// stage 32 KB B-chunk (128 k x 128 d half) with inverse-swizzled source
#define STAGE_B(dst, kcc, hh)                                                 \
    {                                                                         \
        _Pragma("unroll")                                                     \
        for (int r = 0; r < 4; ++r) {                                         \
            const int c   = r * 512 + tid;                                    \
            const int row = c >> 4;                                           \
            const int col = (((c & 15) ^ (row & 15)) << 3);                   \
            GLOAD_LDS16(e16 + ((size_t)((kcc) * 128 + row)) * Dn + (hh) * 128 + col, \
                        (dst) + ((r * 512 + (wid << 6)) << 3));               \
        }                                                                     \
    }

// plain accumulate phase (d-half via afArr, B from bbuf)
#define COMPUTE_ACC(bbuf, afArr)                                              \
    {                                                                         \
        __builtin_amdgcn_s_setprio(1);                                        \
        _Pragma("unroll")                                                     \
        for (int ks = 0; ks < 4; ++ks)                                        \
            _Pragma("unroll")                                                 \
            for (int j = 0; j < 8; ++j) {                                     \
                const f16x8 bf = *(const f16x8*)(                             \
                    &(bbuf)[((j << 4) + l15) * 128 +                          \
                            ((((ks << 2) | quad) ^ l15) << 3)]);              \
                _Pragma("unroll")                                             \
                for (int i = 0; i < 2; ++i)                                   \
                    acc[i][j] = __builtin_amdgcn_mfma_f32_16x16x32_f16(       \
                        afArr[ks * 2 + i], bf, acc[i][j], 0, 0, 0);           \
            }                                                                 \
        __builtin_amdgcn_s_setprio(0);                                        \
    }

__global__ __launch_bounds__(512, 2) void gemm_argmax(
    const float* __restrict__ x, const ushort_t* __restrict__ e16,
    const float* __restrict__ bias_g, const float* __restrict__ emb,
    int* __restrict__ codes_i, float* __restrict__ codes_f,
    int* __restrict__ list, int* __restrict__ counter,
    float* __restrict__ decoded)
{
    __shared__ __align__(16) ushort_t BsS[2][128 * 128]; // 2 x 32 KB
    __shared__ __align__(16) float    biasLds[2048];     // 8 KB
    __shared__ int codeLds[256];                         // 1 KB

    const int bid = blockIdx.x;          // 256 blocks: one 256-t tile each
    const int b   = bid >> 4;
    const int tt  = bid & 15;
    const int t0  = tt << 8;

    const int tid  = threadIdx.x;
    const int lane = tid & 63;
    const int wid  = tid >> 6;           // 8 waves, each owns 32 t-rows
    const int l15  = lane & 15;
    const int quad = lane >> 4;
    const int wm   = wid;                // t-block of 32 rows

    const size_t bTt0 = (size_t)b * Tn + t0;

    // ---- prologue: bias -> LDS; A -> registers directly from x ----
    GLOAD_LDS16(bias_g + (tid << 2), biasLds + (wid << 8));   // 1 outstanding

    // persistent A fragments: 2 halves x (4 ks x 2 i) = 16 f16x8 = 64 VGPR
    f16x8 af0[8], af1[8];
    {
        const float* xb = x + (size_t)b * Dn * Tn;   // [D][T]
        #pragma unroll
        for (int ks = 0; ks < 4; ++ks)
            #pragma unroll
            for (int i = 0; i < 2; ++i) {
                const int t = t0 + (wm << 5) + (i << 4) + l15;
                const float* c0 = xb + ((size_t)(ks * 32 + quad * 8)) * Tn + t;
                const float* c1 = c0 + (size_t)128 * Tn;
                f16x8 v0, v1;
                #pragma unroll
                for (int e = 0; e < 8; ++e) {
                    v0[e] = (_Float16)c0[(size_t)e * Tn];
                    v1[e] = (_Float16)c1[(size_t)e * Tn];
                }
                af0[ks * 2 + i] = v0;
                af1[ks * 2 + i] = v1;
            }
    }

    // accumulators: 2 i x 8 j = 64 regs
    f32x4 acc[2][8];
    // top-2 state per (i,r): 24 regs
    float S1[2][4], S2[2][4];
    int   K1[2][4];
    #pragma unroll
    for (int i = 0; i < 2; ++i)
        #pragma unroll
        for (int r = 0; r < 4; ++r) { S1[i][r] = -INFINITY; S2[i][r] = -INFINITY; K1[i][r] = 0; }
    #pragma unroll
    for (int i = 0; i < 2; ++i)
        #pragma unroll
        for (int j = 0; j < 8; ++j)
            acc[i][j] = (f32x4){-INFINITY, -INFINITY, -INFINITY, -INFINITY};

    asm volatile("s_waitcnt vmcnt(0)" ::: "memory");   // bias + A loads landed
    BARRIER_PIN();                                     // biasLds visible
    STAGE_B(&BsS[0][0], 0, 0);                         // 4
    STAGE_B(&BsS[1][0], 0, 1);                         // 4 -> 8 outstanding

    #pragma unroll 1
    for (int kc = 0; kc < 16; ++kc) {
        // ---- phase h0 (d 0..127, Bs0): drain prev-kc acc + C=-bias re-init --
        asm volatile("s_waitcnt vmcnt(4)" ::: "memory");
        BARRIER_PIN();
        {
            float bj[8];
            #pragma unroll
            for (int j = 0; j < 8; ++j)
                bj[j] = biasLds[(kc << 7) + (j << 4) + l15];
            const int kdrb = ((kc - 1) << 7) + l15;   // k of drained values
            __builtin_amdgcn_s_setprio(1);
            #pragma unroll
            for (int j = 0; j < 8; ++j) {
                const f16x8 bf0 = *(const f16x8*)(
                    &BsS[0][((j << 4) + l15) * 128 + ((quad ^ l15) << 3)]);
                const float nb = -bj[j];
                const f32x4 cin = {nb, nb, nb, nb};
                const int kdr = kdrb + (j << 4);
                #pragma unroll
                for (int i = 0; i < 2; ++i) {
                    // drain old acc[i][j]: med3 top-2 insert (kc==0: -INF, harmless)
                    #pragma unroll
                    for (int r = 0; r < 4; ++r) {
                        const float s = acc[i][j][r];
                        S2[i][r] = __builtin_amdgcn_fmed3f(s, S1[i][r], S2[i][r]);
                        const bool gt = s > S1[i][r];
                        K1[i][r] = gt ? kdr : K1[i][r];
                        S1[i][r] = fmaxf(S1[i][r], s);
                    }
                    acc[i][j] = __builtin_amdgcn_mfma_f32_16x16x32_f16(
                        af0[i], bf0, cin, 0, 0, 0);
                }
            }
            #pragma unroll
            for (int ks = 1; ks < 4; ++ks)
                #pragma unroll
                for (int j = 0; j < 8; ++j) {
                    const f16x8 bf = *(const f16x8*)(
                        &BsS[0][((j << 4) + l15) * 128 +
                                ((((ks << 2) | quad) ^ l15) << 3)]);
                    #pragma unroll
                    for (int i = 0; i < 2; ++i)
                        acc[i][j] = __builtin_amdgcn_mfma_f32_16x16x32_f16(
                            af0[ks * 2 + i], bf, acc[i][j], 0, 0, 0);
                }
            __builtin_amdgcn_s_setprio(0);
        }
        BARRIER_PIN();                       // WAR: Bs0 readers done
        if (kc < 15) STAGE_B(&BsS[0][0], kc + 1, 0);

        // ---- phase h1 (d 128..255, Bs1): plain accumulate ----
        if (kc < 15) { asm volatile("s_waitcnt vmcnt(4)" ::: "memory"); }
        else         { asm volatile("s_waitcnt vmcnt(0)" ::: "memory"); }
        BARRIER_PIN();
        COMPUTE_ACC((&BsS[1][0]), af1);
        BARRIER_PIN();                       // WAR: Bs1 readers done
        if (kc < 15) STAGE_B(&BsS[1][0], kc + 1, 1);
    }

    __builtin_amdgcn_sched_barrier(0);

    // ---- final drain of kc=15 acc ----
    {
        const int kfb = (15 << 7) + l15;
        #pragma unroll
        for (int j = 0; j < 8; ++j) {
            const int kf = kfb + (j << 4);
            #pragma unroll
            for (int i = 0; i < 2; ++i)
                #pragma unroll
                for (int r = 0; r < 4; ++r) {
                    const float s = acc[i][j][r];
                    S2[i][r] = __builtin_amdgcn_fmed3f(s, S1[i][r], S2[i][r]);
                    const bool gt = s > S1[i][r];
                    K1[i][r] = gt ? kf : K1[i][r];
                    S1[i][r] = fmaxf(S1[i][r], s);
                }
        }
    }

    // ---- butterfly across the 16 k-lanes (tie-break: lowest k) ----
    #pragma unroll
    for (int m = 1; m <= 8; m <<= 1) {
        #pragma unroll
        for (int i = 0; i < 2; ++i)
            #pragma unroll
            for (int r = 0; r < 4; ++r) {
                const float os1 = __shfl_xor(S1[i][r], m);
                const float os2 = __shfl_xor(S2[i][r], m);
                const int   ok1 = __shfl_xor(K1[i][r], m);
                const bool take = (os1 > S1[i][r]) || (os1 == S1[i][r] && ok1 < K1[i][r]);
                const float ns2 = take ? fmaxf(S1[i][r], os2) : fmaxf(S2[i][r], os1);
                if (take) { S1[i][r] = os1; K1[i][r] = ok1; }
                S2[i][r] = ns2;
            }
    }

    if (l15 == 0) {
        #pragma unroll
        for (int i = 0; i < 2; ++i)
            #pragma unroll
            for (int r = 0; r < 4; ++r) {
                const int row = (wm << 5) + (i << 4) + (quad << 2) + r;
                const size_t p = bTt0 + row;
                const int wk = K1[i][r];
                codeLds[row] = wk;
                codes_i[p] = wk;
                codes_f[p] = (float)wk;
                if (S1[i][r] - S2[i][r] < TAU) {
                    const int idx = atomicAdd(counter, 1);
                    list[idx] = (int)p;
                }
            }
    }
    __syncthreads();

    // ---- fused decode: this block's 256 columns of decoded[b][:, t0..] ----
    // thread (p2 = tid&255, dh = tid>>8) writes 128 d-values for point p2;
    // for fixed d, 256 lanes hit 256 consecutive t -> coalesced stores.
    {
        const int p2 = tid & 255;
        const int dh = tid >> 8;                       // 0 or 1 (d-half)
        const int c  = codeLds[p2];
        const float4* e4 = (const float4*)(emb + (size_t)c * Dn) + dh * 32;
        float* ob = decoded + ((size_t)(b * Dn + dh * 128)) * Tn + t0 + p2;
        #pragma unroll 4
        for (int q = 0; q < 32; ++q) {
            const float4 v = e4[q];
            ob[(size_t)(q * 4 + 0) * Tn] = v.x;
            ob[(size_t)(q * 4 + 1) * Tn] = v.y;
            ob[(size_t)(q * 4 + 2) * Tn] = v.z;
            ob[(size_t)(q * 4 + 3) * Tn] = v.w;
        }
    }
}

// ---------------------------------------------------------------------------
// Kernel 5: exact fp32 rescore + decoded-column fixup for rescued points.
// ---------------------------------------------------------------------------
__global__ __launch_bounds__(256) void rescue_kernel(
    const float* __restrict__ x, const float4* __restrict__ embT4,
    const float* __restrict__ bias, const float* __restrict__ emb,
    const int* __restrict__ list, const int* __restrict__ counter,
    int* __restrict__ codes_i, float* __restrict__ codes_f,
    float* __restrict__ decoded)
{
    __shared__ float xv[RP][256];
    __shared__ int plist[RP];
    __shared__ float rs[RP][4];
    __shared__ int   rk[RP][4];
    __shared__ int   fcode[RP];
    const int tid = threadIdx.x, lane = tid & 63, wid = tid >> 6;
    const int count = *counter;
    for (int base = blockIdx.x * RP; base < count; base += gridDim.x * RP) {
        const int npts = min(RP, count - base);
        __syncthreads();
        if (tid < npts) plist[tid] = list[base + tid];
        __syncthreads();
        for (int pi = 0; pi < npts; ++pi) {
            const int p = plist[pi];
            xv[pi][tid] = x[((size_t)((p >> 12) * Dn + tid)) * Tn + (p & 4095)];
        }
        for (int pi = npts; pi < RP; ++pi) xv[pi][tid] = 0.f;
        __syncthreads();

        float acc[8][RP];
        #pragma unroll
        for (int s = 0; s < 8; ++s)
            #pragma unroll
            for (int pi = 0; pi < RP; ++pi) acc[s][pi] = 0.f;

        for (int dc = 0; dc < 64; ++dc) {
            float4 ev[8];
            #pragma unroll
            for (int s = 0; s < 8; ++s)
                ev[s] = embT4[(size_t)dc * Kn + tid + (s << 8)];
            #pragma unroll
            for (int pi = 0; pi < RP; ++pi) {
                const float4 xw = *(const float4*)&xv[pi][dc << 2];
                #pragma unroll
                for (int s = 0; s < 8; ++s)
                    acc[s][pi] += ev[s].x * xw.x + ev[s].y * xw.y
                                + ev[s].z * xw.z + ev[s].w * xw.w;
            }
        }

        float bs[RP]; int bk[RP];
        #pragma unroll
        for (int pi = 0; pi < RP; ++pi) { bs[pi] = -INFINITY; bk[pi] = 0; }
        #pragma unroll
        for (int s = 0; s < 8; ++s) {
            const int kk = tid + (s << 8);
            const float bv = bias[kk];
            #pragma unroll
            for (int pi = 0; pi < RP; ++pi) {
                const float sc = acc[s][pi] - bv;
                if (sc > bs[pi]) { bs[pi] = sc; bk[pi] = kk; }
            }
        }
        #pragma unroll
        for (int off = 1; off < 64; off <<= 1) {
            #pragma unroll
            for (int pi = 0; pi < RP; ++pi) {
                const float os = __shfl_xor(bs[pi], off);
                const int   ok = __shfl_xor(bk[pi], off);
                if (os > bs[pi] || (os == bs[pi] && ok < bk[pi])) { bs[pi] = os; bk[pi] = ok; }
            }
        }
        if (lane == 0) {
            #pragma unroll
            for (int pi = 0; pi < RP; ++pi) { rs[pi][wid] = bs[pi]; rk[pi][wid] = bk[pi]; }
        }
        __syncthreads();
        if (tid < npts) {
            float fs = rs[tid][0]; int fk = rk[tid][0];
            #pragma unroll
            for (int w = 1; w < 4; ++w) {
                if (rs[tid][w] > fs || (rs[tid][w] == fs && rk[tid][w] < fk)) {
                    fs = rs[tid][w]; fk = rk[tid][w];
                }
            }
            const int p = plist[tid];
            codes_i[p] = fk;
            codes_f[p] = (float)fk;
            fcode[tid] = fk;
        }
        __syncthreads();
        // decoded fixup: all 256 threads rewrite column d=tid for each point
        for (int pi = 0; pi < npts; ++pi) {
            const int p = plist[pi];
            const int c = fcode[pi];
            decoded[((size_t)((p >> 12) * Dn + tid)) * Tn + (p & 4095)] =
                emb[(size_t)c * Dn + tid];
        }
    }
}

// ---------------------------------------------------------------------------
extern "C" void kernel_launch(void* const* d_in, const int* in_sizes, int n_in,
                              void* d_out, int out_size, void* d_ws, size_t ws_size,
                              hipStream_t stream) {
    const float* x     = (const float*)d_in[0];   // [B, D, T]
    const float* es    = (const float*)d_in[1];   // [K, D]
    const float* usage = (const float*)d_in[2];   // [K]

    // ws layout (byte offsets, 16-aligned) — ~6 MiB
    char* ws = (char*)d_ws;
    float*    emb     = (float*)(ws + 0);                // 2 MiB
    float*    bias    = (float*)(ws + 2097152);          // 8 KB
    ushort_t* e16     = (ushort_t*)(ws + 2105344);       // 1 MiB
    float4*   embT4   = (float4*)(ws + 3153920);         // 2 MiB
    int*      codes_i = (int*)(ws + 5251072);            // 256 KB
    int*      list    = (int*)(ws + 5513216);            // 256 KB
    int*      counter = (int*)(ws + 5775360);            // 4 B

    float* codes_f = (float*)d_out;                      // [B*T]
    float* decoded = (float*)d_out + (size_t)Bn * Tn;    // [B*D*T], 64 MiB

    prep_kernel<<<Kn, 256, 0, stream>>>(es, usage, emb, e16, bias, embT4, counter);

    // 256 blocks of 512 thr (1/CU), each: 256 t x full K=2048, A in regs,
    // codes + decoded written in-kernel (decode kernel fused away)
    gemm_argmax<<<256, 512, 0, stream>>>(x, e16, bias, emb, codes_i, codes_f,
                                         list, counter, decoded);

    rescue_kernel<<<1024, 256, 0, stream>>>(x, embT4, bias, emb, list, counter,
                                            codes_i, codes_f, decoded);
}